// Round 1
// baseline (452.932 us; speedup 1.0000x reference)
//
#include <hip/hip_runtime.h>

// SubsetSampler: out0 = x (f32 passthrough), out1 = float(mask | (l >= cutoff)),
// cutoff_b = min(ceil(0.7 * count_false(mask[b,:])), L-1).
// Shapes fixed by the reference: B=8192, L=4096 (B derived from in_sizes[0]/L).

#define L_DIM 4096
#define SUBSET_RATE 0.7f

// ---- mask-storage detection -------------------------------------------------
// The harness's on-device layout for a bool input is not documented. Tail-padding
// masks let us detect it from content:
//   * byte bools: runs of 0x01 bytes -> some aligned word > 1 within the first
//     4 rows (first 4096 words) with probability ~1 - (7/4096)^4.
//   * float32 bools: words are 0x00000000 / 0x3f800000.
//   * int32 bools: words are 0 / 1 only.
// Word-sized layouts (int32, f32) share one decode path (nonzero == True),
// so we only need byte-vs-word. mode: 1 = 1-byte elems, 0 = 4-byte elems.
__global__ void detect_mode_kernel(const unsigned int* __restrict__ m,
                                   int* __restrict__ mode) {
    __shared__ int any_gt1, any_f32;
    if (threadIdx.x == 0) { any_gt1 = 0; any_f32 = 0; }
    __syncthreads();
    int lgt1 = 0, lf32 = 0;
    for (int i = threadIdx.x; i < L_DIM; i += blockDim.x) {
        unsigned int w = m[i];
        if (w == 0x3f800000u)      lf32 = 1;
        else if (w > 1u)           lgt1 = 1;
    }
    if (lgt1) any_gt1 = 1;   // benign same-value race
    if (lf32) any_f32 = 1;
    __syncthreads();
    if (threadIdx.x == 0)
        *mode = (any_f32 ? 0 : (any_gt1 ? 1 : 0));
}

// ---- main kernel ------------------------------------------------------------
// One block per row, 256 threads; thread t owns elements [16t, 16t+16).
// Phase 1: count False (zeros) + keep 16-bit mask in a register.
// Block reduce -> length -> cutoff (exact f32 arithmetic to match jnp).
// Phase 2: float4 copy x, float4 write mask-as-float.
__global__ __launch_bounds__(256)
void subset_kernel(const float* __restrict__ x,
                   const void* __restrict__ mask,
                   const int* __restrict__ mode_p,
                   float* __restrict__ out_x,
                   float* __restrict__ out_mask) {
    const int row  = blockIdx.x;
    const int t    = threadIdx.x;
    const int base = t * 16;          // first element this thread owns
    const int mode = *mode_p;         // wave-uniform scalar load

    unsigned int bits = 0;            // bit j = mask value of element base+j
    int zeros = 0;

    if (mode == 1) {
        // 1-byte bools: one uint4 (16 bytes) covers all 16 elements.
        const uint4* mp = (const uint4*)((const unsigned char*)mask + (size_t)row * L_DIM);
        uint4 w = mp[t];
        unsigned int ws[4] = {w.x, w.y, w.z, w.w};
        #pragma unroll
        for (int k = 0; k < 4; ++k) {
            #pragma unroll
            for (int j = 0; j < 4; ++j) {
                unsigned int byte = (ws[k] >> (8 * j)) & 0xffu;
                if (byte) bits |= (1u << (k * 4 + j));
                else      zeros++;
            }
        }
    } else {
        // 4-byte elements (int32 0/1 or f32 0.0/1.0): nonzero word == True.
        const uint4* mp = (const uint4*)((const unsigned int*)mask + (size_t)row * L_DIM);
        #pragma unroll
        for (int k = 0; k < 4; ++k) {
            uint4 w = mp[t * 4 + k];
            unsigned int ws[4] = {w.x, w.y, w.z, w.w};
            #pragma unroll
            for (int j = 0; j < 4; ++j) {
                if (ws[j]) bits |= (1u << (k * 4 + j));
                else       zeros++;
            }
        }
    }

    // ---- block reduction of zero-count (wave64 shuffle + LDS) ----
    #pragma unroll
    for (int off = 32; off > 0; off >>= 1)
        zeros += __shfl_down(zeros, off, 64);
    __shared__ int partial[4];
    __shared__ int cutoff_s;
    if ((t & 63) == 0) partial[t >> 6] = zeros;
    __syncthreads();
    if (t == 0) {
        int len = partial[0] + partial[1] + partial[2] + partial[3];
        // exact match to jnp: f32 multiply (one rounding), f32 ceil, min
        int cut = (int)ceilf((float)len * SUBSET_RATE);
        cutoff_s = min(cut, L_DIM - 1);
    }
    __syncthreads();
    const int cutoff = cutoff_s;

    // ---- phase 2: vectorized writes ----
    const float4* xr  = (const float4*)(x        + (size_t)row * L_DIM);
    float4*       oxr = (float4*)      (out_x    + (size_t)row * L_DIM);
    float4*       omr = (float4*)      (out_mask + (size_t)row * L_DIM);
    #pragma unroll
    for (int k = 0; k < 4; ++k) {
        oxr[t * 4 + k] = xr[t * 4 + k];
        const int i0 = base + 4 * k;
        float4 mv;
        mv.x = (((bits >> (4 * k + 0)) & 1u) || (i0 + 0 >= cutoff)) ? 1.0f : 0.0f;
        mv.y = (((bits >> (4 * k + 1)) & 1u) || (i0 + 1 >= cutoff)) ? 1.0f : 0.0f;
        mv.z = (((bits >> (4 * k + 2)) & 1u) || (i0 + 2 >= cutoff)) ? 1.0f : 0.0f;
        mv.w = (((bits >> (4 * k + 3)) & 1u) || (i0 + 3 >= cutoff)) ? 1.0f : 0.0f;
        omr[t * 4 + k] = mv;
    }
}

extern "C" void kernel_launch(void* const* d_in, const int* in_sizes, int n_in,
                              void* d_out, int out_size, void* d_ws, size_t ws_size,
                              hipStream_t stream) {
    const float* x    = (const float*)d_in[0];
    const void*  mask = d_in[1];
    const int B = in_sizes[0] / L_DIM;          // 8192

    float* out_x    = (float*)d_out;            // first B*L floats
    float* out_mask = out_x + (size_t)B * L_DIM; // next B*L floats (0.0/1.0)
    int*   mode     = (int*)d_ws;               // ws re-poisoned every call; we always rewrite

    detect_mode_kernel<<<1, 256, 0, stream>>>((const unsigned int*)mask, mode);
    subset_kernel<<<B, 256, 0, stream>>>(x, mask, mode, out_x, out_mask);
}

// Round 2
// 439.614 us; speedup vs baseline: 1.0303x; 1.0303x over previous
//
#include <hip/hip_runtime.h>

// SubsetSampler: out0 = x (f32 passthrough), out1 = float(mask | (l >= cutoff)),
// cutoff_b = min(ceil(0.7 * count_false(mask[b,:])), L-1).
// B=8192, L=4096 (B derived from in_sizes[0]/L).
//
// R1 fix: interleaved chunk ownership (thread t owns float4 chunks t+256k)
// so every wave memory instruction is a contiguous 4 KB span. The R0 version
// gave each thread a contiguous 16-element range -> 64B-stride access on all
// three big streams -> request-rate-bound at ~1 TB/s.

#define L_DIM 4096
#define SUBSET_RATE 0.7f

// ---- mask-storage detection (unchanged from R1; ~4 us, 16 KB read) ----------
// byte bools: tail runs of 0x01 -> some word > 1 in first 4096 words (first
// 4 byte-rows) with prob ~1-(7/4096)^4. f32 bools: word 0x3f800000.
// int32 bools: words 0/1 only. Word-sized layouts share the decode path.
__global__ void detect_mode_kernel(const unsigned int* __restrict__ m,
                                   int* __restrict__ mode) {
    __shared__ int any_gt1, any_f32;
    if (threadIdx.x == 0) { any_gt1 = 0; any_f32 = 0; }
    __syncthreads();
    int lgt1 = 0, lf32 = 0;
    for (int i = threadIdx.x; i < L_DIM; i += blockDim.x) {
        unsigned int w = m[i];
        if (w == 0x3f800000u)      lf32 = 1;
        else if (w > 1u)           lgt1 = 1;
    }
    if (lgt1) any_gt1 = 1;   // benign same-value race
    if (lf32) any_f32 = 1;
    __syncthreads();
    if (threadIdx.x == 0)
        *mode = (any_f32 ? 0 : (any_gt1 ? 1 : 0));
}

// ---- main kernel ------------------------------------------------------------
// One block per row, 256 threads. Thread t owns float4 chunks c = t + 256*k,
// k=0..3 (elements 4c..4c+3). Phase 1: decode mask chunk into a 16-bit reg
// bitmask AND stream-copy the x chunk (cutoff-independent). Block reduce
// zero-count -> cutoff. Phase 2: coalesced float4 mask writes.
__global__ __launch_bounds__(256)
void subset_kernel(const float* __restrict__ x,
                   const void* __restrict__ mask,
                   const int* __restrict__ mode_p,
                   float* __restrict__ out_x,
                   float* __restrict__ out_mask) {
    const int row  = blockIdx.x;
    const int t    = threadIdx.x;
    const int mode = *mode_p;                 // wave-uniform scalar load
    const size_t rowoff = (size_t)row * L_DIM;

    const float4* xr  = (const float4*)(x        + rowoff);
    float4*       oxr = (float4*)      (out_x    + rowoff);
    float4*       omr = (float4*)      (out_mask + rowoff);

    unsigned int bits = 0;   // bit (4k+j) = mask value of element 4*(t+256k)+j

    if (mode == 1) {
        // 1-byte bools: uint32 at word index c covers the chunk's 4 elements.
        const unsigned int* mp =
            (const unsigned int*)((const unsigned char*)mask + rowoff);
        #pragma unroll
        for (int k = 0; k < 4; ++k) {
            const int c = t + 256 * k;
            unsigned int w = mp[c];
            #pragma unroll
            for (int j = 0; j < 4; ++j)
                if ((w >> (8 * j)) & 0xffu) bits |= 1u << (4 * k + j);
            oxr[c] = xr[c];                   // coalesced 4 KB/wave-instr
        }
    } else {
        // 4-byte elements (int32 0/1 or f32): uint4 per chunk, 16 B/lane.
        const uint4* mp = (const uint4*)((const unsigned int*)mask + rowoff);
        #pragma unroll
        for (int k = 0; k < 4; ++k) {
            const int c = t + 256 * k;
            uint4 w = mp[c];
            if (w.x) bits |= 1u << (4 * k + 0);
            if (w.y) bits |= 1u << (4 * k + 1);
            if (w.z) bits |= 1u << (4 * k + 2);
            if (w.w) bits |= 1u << (4 * k + 3);
            oxr[c] = xr[c];
        }
    }

    int zeros = 16 - __popc(bits);            // False count this thread saw

    // ---- block reduction (wave64 shuffle + LDS) ----
    #pragma unroll
    for (int off = 32; off > 0; off >>= 1)
        zeros += __shfl_down(zeros, off, 64);
    __shared__ int partial[4];
    __shared__ int cutoff_s;
    if ((t & 63) == 0) partial[t >> 6] = zeros;
    __syncthreads();
    if (t == 0) {
        int len = partial[0] + partial[1] + partial[2] + partial[3];
        // exact match to jnp: f32 multiply (one rounding), f32 ceil, min
        cutoff_s = min((int)ceilf((float)len * SUBSET_RATE), L_DIM - 1);
    }
    __syncthreads();
    const int cutoff = cutoff_s;

    // ---- phase 2: coalesced mask writes ----
    #pragma unroll
    for (int k = 0; k < 4; ++k) {
        const int c  = t + 256 * k;
        const int i0 = c * 4;
        float4 mv;
        mv.x = (((bits >> (4 * k + 0)) & 1u) || (i0 + 0 >= cutoff)) ? 1.0f : 0.0f;
        mv.y = (((bits >> (4 * k + 1)) & 1u) || (i0 + 1 >= cutoff)) ? 1.0f : 0.0f;
        mv.z = (((bits >> (4 * k + 2)) & 1u) || (i0 + 2 >= cutoff)) ? 1.0f : 0.0f;
        mv.w = (((bits >> (4 * k + 3)) & 1u) || (i0 + 3 >= cutoff)) ? 1.0f : 0.0f;
        omr[c] = mv;
    }
}

extern "C" void kernel_launch(void* const* d_in, const int* in_sizes, int n_in,
                              void* d_out, int out_size, void* d_ws, size_t ws_size,
                              hipStream_t stream) {
    const float* x    = (const float*)d_in[0];
    const void*  mask = d_in[1];
    const int B = in_sizes[0] / L_DIM;            // 8192

    float* out_x    = (float*)d_out;              // first B*L floats
    float* out_mask = out_x + (size_t)B * L_DIM;  // next B*L floats (0.0/1.0)
    int*   mode     = (int*)d_ws;                 // rewritten every call

    detect_mode_kernel<<<1, 256, 0, stream>>>((const unsigned int*)mask, mode);
    subset_kernel<<<B, 256, 0, stream>>>(x, mask, mode, out_x, out_mask);
}

// Round 4
// 420.285 us; speedup vs baseline: 1.0777x; 1.0460x over previous
//
#include <hip/hip_runtime.h>

// SubsetSampler: out0 = x (f32 passthrough), out1 = float(mask | (l >= cutoff)),
// cutoff_b = min(ceil(0.7 * count_false(mask[b,:])), L-1).  B=8192, L=4096.
//
// R2 analysis: dur_us includes ~335 us of harness-fixed poison/restore traffic
// (1 GiB fillBuffer at 6.5 TB/s dominates the profile). Controllable part is
// the subset kernel (~100 us, traffic floor ~85 us @ 536 MB) + detect (~5 us).
// R4 = R3 with compile fix: __builtin_nontemporal_* rejects HIP_vector_type
// (a C++ class); use native clang ext_vector_type(4) instead.

#define L_DIM 4096
#define SUBSET_RATE 0.7f

typedef float        f32x4 __attribute__((ext_vector_type(4)));
typedef unsigned int u32x4 __attribute__((ext_vector_type(4)));

// ---- mask-storage detection (1 block, 16 KB read, ~5 us) --------------------
// byte bools: padding runs of 0x01 -> some word > 1 in the first 4096 words.
// f32 bools: word 0x3f800000. int32 bools: words 0/1 only. Word-sized layouts
// (int32/f32) share the decode path (nonzero == True). mode: 1=bytes, 0=words.
__global__ void detect_mode_kernel(const unsigned int* __restrict__ m,
                                   int* __restrict__ mode) {
    __shared__ int any_gt1, any_f32;
    if (threadIdx.x == 0) { any_gt1 = 0; any_f32 = 0; }
    __syncthreads();
    int lgt1 = 0, lf32 = 0;
    for (int i = threadIdx.x; i < L_DIM; i += blockDim.x) {
        unsigned int w = m[i];
        if (w == 0x3f800000u)      lf32 = 1;
        else if (w > 1u)           lgt1 = 1;
    }
    if (lgt1) any_gt1 = 1;   // benign same-value race
    if (lf32) any_f32 = 1;
    __syncthreads();
    if (threadIdx.x == 0)
        *mode = (any_f32 ? 0 : (any_gt1 ? 1 : 0));
}

// ---- main kernel ------------------------------------------------------------
// One block per row, 256 threads. Thread t owns float4 chunks c = t + 256*k,
// k=0..3 (elements 4c..4c+3) -> every wave memory instr spans contiguous 4 KB.
__global__ __launch_bounds__(256)
void subset_kernel(const float* __restrict__ x,
                   const void* __restrict__ mask,
                   const int* __restrict__ mode_p,
                   float* __restrict__ out_x,
                   float* __restrict__ out_mask) {
    const int row  = blockIdx.x;
    const int t    = threadIdx.x;
    const int mode = *mode_p;                 // wave-uniform scalar load
    const size_t rowoff = (size_t)row * L_DIM;

    const f32x4* xr  = (const f32x4*)(x        + rowoff);
    f32x4*       oxr = (f32x4*)      (out_x    + rowoff);
    f32x4*       omr = (f32x4*)      (out_mask + rowoff);

    unsigned int bits = 0;   // bit (4k+j) = mask value of element 4*(t+256k)+j

    if (mode == 1) {
        // 1-byte bools: uint32 at word index c covers the chunk's 4 elements.
        const unsigned int* mp =
            (const unsigned int*)((const unsigned char*)mask + rowoff);
        unsigned int mw[4];
        #pragma unroll
        for (int k = 0; k < 4; ++k)                       // mask loads first:
            mw[k] = __builtin_nontemporal_load(&mp[t + 256 * k]);
        f32x4 xv[4];
        #pragma unroll
        for (int k = 0; k < 4; ++k)                       // x loads overlap
            xv[k] = __builtin_nontemporal_load(&xr[t + 256 * k]);
        #pragma unroll
        for (int k = 0; k < 4; ++k) {
            #pragma unroll
            for (int j = 0; j < 4; ++j)
                if ((mw[k] >> (8 * j)) & 0xffu) bits |= 1u << (4 * k + j);
        }
        #pragma unroll
        for (int k = 0; k < 4; ++k)
            __builtin_nontemporal_store(xv[k], &oxr[t + 256 * k]);
    } else {
        // 4-byte elements (int32 0/1 or f32 bits): nonzero word == True.
        const u32x4* mp = (const u32x4*)((const unsigned int*)mask + rowoff);
        u32x4 mw[4];
        #pragma unroll
        for (int k = 0; k < 4; ++k)
            mw[k] = __builtin_nontemporal_load(&mp[t + 256 * k]);
        f32x4 xv[4];
        #pragma unroll
        for (int k = 0; k < 4; ++k)
            xv[k] = __builtin_nontemporal_load(&xr[t + 256 * k]);
        #pragma unroll
        for (int k = 0; k < 4; ++k) {
            if (mw[k].x) bits |= 1u << (4 * k + 0);
            if (mw[k].y) bits |= 1u << (4 * k + 1);
            if (mw[k].z) bits |= 1u << (4 * k + 2);
            if (mw[k].w) bits |= 1u << (4 * k + 3);
        }
        #pragma unroll
        for (int k = 0; k < 4; ++k)
            __builtin_nontemporal_store(xv[k], &oxr[t + 256 * k]);
    }

    int zeros = 16 - __popc(bits);            // False count this thread saw

    // ---- block reduction (wave64 shuffle + LDS) ----
    #pragma unroll
    for (int off = 32; off > 0; off >>= 1)
        zeros += __shfl_down(zeros, off, 64);
    __shared__ int partial[4];
    __shared__ int cutoff_s;
    if ((t & 63) == 0) partial[t >> 6] = zeros;
    __syncthreads();
    if (t == 0) {
        int len = partial[0] + partial[1] + partial[2] + partial[3];
        // exact match to jnp: f32 multiply (one rounding), f32 ceil, min
        cutoff_s = min((int)ceilf((float)len * SUBSET_RATE), L_DIM - 1);
    }
    __syncthreads();
    const int cutoff = cutoff_s;

    // ---- coalesced nontemporal mask writes ----
    #pragma unroll
    for (int k = 0; k < 4; ++k) {
        const int c  = t + 256 * k;
        const int i0 = c * 4;
        f32x4 mv;
        mv.x = (((bits >> (4 * k + 0)) & 1u) || (i0 + 0 >= cutoff)) ? 1.0f : 0.0f;
        mv.y = (((bits >> (4 * k + 1)) & 1u) || (i0 + 1 >= cutoff)) ? 1.0f : 0.0f;
        mv.z = (((bits >> (4 * k + 2)) & 1u) || (i0 + 2 >= cutoff)) ? 1.0f : 0.0f;
        mv.w = (((bits >> (4 * k + 3)) & 1u) || (i0 + 3 >= cutoff)) ? 1.0f : 0.0f;
        __builtin_nontemporal_store(mv, &omr[c]);
    }
}

extern "C" void kernel_launch(void* const* d_in, const int* in_sizes, int n_in,
                              void* d_out, int out_size, void* d_ws, size_t ws_size,
                              hipStream_t stream) {
    const float* x    = (const float*)d_in[0];
    const void*  mask = d_in[1];
    const int B = in_sizes[0] / L_DIM;            // 8192

    float* out_x    = (float*)d_out;              // first B*L floats
    float* out_mask = out_x + (size_t)B * L_DIM;  // next B*L floats (0.0/1.0)
    int*   mode     = (int*)d_ws;                 // rewritten every call

    detect_mode_kernel<<<1, 256, 0, stream>>>((const unsigned int*)mask, mode);
    subset_kernel<<<B, 256, 0, stream>>>(x, mask, mode, out_x, out_mask);
}